// Round 1
// baseline (42624.478 us; speedup 1.0000x reference)
//
#include <hip/hip_runtime.h>

#define EPSF 1e-5f

__device__ __forceinline__ float bf2f(unsigned short u) {
  union { unsigned int i; float f; } v; v.i = ((unsigned int)u) << 16; return v.f;
}

__device__ __forceinline__ unsigned short f2bf(float f) {
  unsigned int u = __float_as_uint(f);
  unsigned int lsb = (u >> 16) & 1u;
  u += 0x7fffu + lsb;           // round-to-nearest-even
  return (unsigned short)(u >> 16);
}

// Convert + transpose weights to bf16 once per call.
// W1: [1024][512] -> W1T[k][j] (512x1024), W2: [512][512] -> W2T[k][j] (512x512)
__global__ void prep_weights(const float* __restrict__ W1, const float* __restrict__ W2,
                             unsigned short* __restrict__ W1T, unsigned short* __restrict__ W2T) {
  int i = blockIdx.x * blockDim.x + threadIdx.x;
  if (i < 1024 * 512) {
    int j = i / 512, k = i % 512;
    W1T[k * 1024 + j] = f2bf(W1[i]);
  }
  if (i < 512 * 512) {
    int j = i / 512, k = i % 512;
    W2T[k * 512 + j] = f2bf(W2[i]);
  }
}

template<bool BF16W>
__global__ __launch_bounds__(1024)
void rnn_kernel(const float* __restrict__ xs, const float* __restrict__ h0,
                const float* __restrict__ gamma, const float* __restrict__ beta,
                const float* __restrict__ W1, const unsigned short* __restrict__ W1T,
                const float* __restrict__ lnh_w, const float* __restrict__ lnh_b,
                const float* __restrict__ W2, const unsigned short* __restrict__ W2T,
                const float* __restrict__ lnx_w, const float* __restrict__ lnx_b,
                float* __restrict__ out) {
  const int b = blockIdx.x;
  const int tid = threadIdx.x;
  const int N = 512, T = 1024;

  __shared__ float h_s[512];
  __shared__ float x_s[512];
  __shared__ float hg_s[512];
  __shared__ float il_s[512];
  __shared__ float red_s[16], red_q[16];
  __shared__ float stat[4];   // mu1, rinv1, mu2, rinv2

  if (tid < N) h_s[tid] = h0[b * N + tid];

  // per-thread persistent parameters
  const int j = tid;                       // mm1 output column 0..1023
  float w1w = lnh_w[j], w1b = lnh_b[j];
  float g0 = 0, g1 = 0, g2 = 0, b0 = 0, b1 = 0, b2 = 0, w2w = 0, w2b = 0;
  if (tid < N) {
    g0 = gamma[0 * N + tid]; g1 = gamma[1 * N + tid]; g2 = gamma[2 * N + tid];
    b0 = beta[0 * N + tid];  b1 = beta[1 * N + tid];  b2 = beta[2 * N + tid];
    w2w = lnx_w[tid]; w2b = lnx_b[tid];
  }
  const float* xs_b = xs + (size_t)b * 3 * N * T;
  const int w = tid >> 6;                  // wave id (16 waves)
  __syncthreads();

  for (int t = 0; t < T; ++t) {
    // ---- in_layer (tid<512): relu(sum_p sigmoid(gamma*h+beta)*xs) ----
    if (tid < N) {
      float hv = h_s[tid];
      float s0 = 1.f / (1.f + __expf(-(g0 * hv + b0)));
      float s1 = 1.f / (1.f + __expf(-(g1 * hv + b1)));
      float s2 = 1.f / (1.f + __expf(-(g2 * hv + b2)));
      float x0 = xs_b[(0 * N + tid) * T + t];
      float x1 = xs_b[(1 * N + tid) * T + t];
      float x2 = xs_b[(2 * N + tid) * T + t];
      il_s[tid] = fmaxf(s0 * x0 + s1 * x1 + s2 * x2, 0.f);
    }

    // ---- mm1: hh_raw[j] = sum_k h[k] * W1[j][k] ----
    float acc = 0.f;
    if (BF16W) {
      const unsigned short* p = W1T + j;
      #pragma unroll 8
      for (int k = 0; k < 512; ++k) {
        acc = fmaf(h_s[k], bf2f(p[0]), acc);
        p += 1024;
      }
    } else {
      const float* p = W1 + (size_t)j * 512;
      #pragma unroll 4
      for (int k = 0; k < 512; ++k) acc = fmaf(h_s[k], p[k], acc);
    }

    // ---- LN1 stats over 1024 cols ----
    {
      float s = acc, q = acc * acc;
      #pragma unroll
      for (int off = 32; off > 0; off >>= 1) {
        s += __shfl_down(s, off); q += __shfl_down(q, off);
      }
      if ((tid & 63) == 0) { red_s[w] = s; red_q[w] = q; }
    }
    __syncthreads();
    if (tid == 0) {
      float ss = 0.f, qq = 0.f;
      #pragma unroll
      for (int i = 0; i < 16; ++i) { ss += red_s[i]; qq += red_q[i]; }
      float mu = ss * (1.f / 1024.f);
      float var = qq * (1.f / 1024.f) - mu * mu;
      stat[0] = mu; stat[1] = rsqrtf(var + EPSF);
    }
    __syncthreads();

    // ---- LN1 apply; build x and h_g ----
    {
      float hh = (acc - stat[0]) * stat[1] * w1w + w1b;
      if (tid < N) x_s[tid] = fmaxf(il_s[tid] + hh, 0.f);
      else         hg_s[tid - N] = hh;
    }
    __syncthreads();

    // ---- mm2: y_raw[n] = sum_k x[k] * W2[n][k]  (tid<512) ----
    float acc2 = 0.f;
    if (tid < N) {
      if (BF16W) {
        const unsigned short* p = W2T + tid;
        #pragma unroll 8
        for (int k = 0; k < 512; ++k) {
          acc2 = fmaf(x_s[k], bf2f(p[0]), acc2);
          p += 512;
        }
      } else {
        const float* p = W2 + (size_t)tid * 512;
        #pragma unroll 4
        for (int k = 0; k < 512; ++k) acc2 = fmaf(x_s[k], p[k], acc2);
      }
    }

    // ---- LN2 stats over 512 cols ----
    {
      float s = (tid < N) ? acc2 : 0.f;
      float q = (tid < N) ? acc2 * acc2 : 0.f;
      #pragma unroll
      for (int off = 32; off > 0; off >>= 1) {
        s += __shfl_down(s, off); q += __shfl_down(q, off);
      }
      if ((tid & 63) == 0) { red_s[w] = s; red_q[w] = q; }
    }
    __syncthreads();
    if (tid == 0) {
      float ss = 0.f, qq = 0.f;
      #pragma unroll
      for (int i = 0; i < 16; ++i) { ss += red_s[i]; qq += red_q[i]; }
      float mu = ss * (1.f / 512.f);
      float var = qq * (1.f / 512.f) - mu * mu;
      stat[2] = mu; stat[3] = rsqrtf(var + EPSF);
    }
    __syncthreads();

    // ---- gate + state update + output ----
    if (tid < N) {
      float y = (acc2 - stat[2]) * stat[3] * w2w + w2b;
      float gg = 1.f / (1.f + __expf(-(y + hg_s[tid])));
      float hn = (1.f - gg) * h_s[tid] + gg * x_s[tid];
      out[((size_t)b * N + tid) * T + t] = hn;
      h_s[tid] = hn;
    }
    __syncthreads();
  }
}

extern "C" void kernel_launch(void* const* d_in, const int* in_sizes, int n_in,
                              void* d_out, int out_size, void* d_ws, size_t ws_size,
                              hipStream_t stream) {
  const float* xs    = (const float*)d_in[0];
  const float* h0    = (const float*)d_in[1];
  const float* gamma = (const float*)d_in[2];
  const float* beta  = (const float*)d_in[3];
  const float* W1    = (const float*)d_in[4];
  const float* lnh_w = (const float*)d_in[5];
  const float* lnh_b = (const float*)d_in[6];
  const float* W2    = (const float*)d_in[7];
  const float* lnx_w = (const float*)d_in[8];
  const float* lnx_b = (const float*)d_in[9];
  float* out = (float*)d_out;

  const size_t need = (size_t)(1024 * 512 + 512 * 512) * sizeof(unsigned short);
  if (ws_size >= need) {
    unsigned short* W1T = (unsigned short*)d_ws;
    unsigned short* W2T = W1T + 1024 * 512;
    const int tot = 1024 * 512;
    prep_weights<<<(tot + 255) / 256, 256, 0, stream>>>(W1, W2, W1T, W2T);
    rnn_kernel<true><<<64, 1024, 0, stream>>>(xs, h0, gamma, beta, W1, W1T,
                                              lnh_w, lnh_b, W2, W2T, lnx_w, lnx_b, out);
  } else {
    rnn_kernel<false><<<64, 1024, 0, stream>>>(xs, h0, gamma, beta, W1, nullptr,
                                               lnh_w, lnh_b, W2, nullptr, lnx_w, lnx_b, out);
  }
}